// Round 8
// baseline (383.265 us; speedup 1.0000x reference)
//
#include <hip/hip_runtime.h>
#include <hip/hip_bf16.h>

#define NN 50000
#define NE 1600000
#define DD 128
#define NPB 64                 // nodes per bucket (dst>>6)
#define NBK 782                // ceil(NN/64)
#define MAXB 2560              // bucket slab capacity (mean 2048, +11 sigma)
#define GRID 448               // < guaranteed co-resident capacity (2/CU x 256 = 512)
#define BLK 512
#define CHUNK 3572             // ceil(NE/GRID): one balanced conv round
#define NCH 448
#define NT 391                 // gemm tiles of 128 rows
#define WS 136                 // gemm LDS row stride (bf16): balanced banks

typedef __attribute__((ext_vector_type(8))) short short8;
typedef __attribute__((ext_vector_type(4))) float f32x4;

__device__ inline unsigned short to_bf16(float v) {
    __hip_bfloat16 h = __float2bfloat16(v);
    return __builtin_bit_cast(unsigned short, h);
}
__device__ inline float bf2f(unsigned short u) {
    return __uint_as_float((unsigned)u << 16);
}

// Device-scope grid barrier. Monotone counter; target = gen*GRID (no reset).
// Spin MUST be an agent-scope atomic load (bypasses L1); a plain/volatile load
// can be served from stale L1 forever. threadfence before arrive = release
// (L2 writeback, cross-XCD); after release = acquire (L1/L2 invalidate).
__device__ inline void gridbar(int* bar, int target) {
    __syncthreads();
    if (threadIdx.x == 0) {
        __threadfence();
        __hip_atomic_fetch_add(bar, 1, __ATOMIC_ACQ_REL, __HIP_MEMORY_SCOPE_AGENT);
        while (__hip_atomic_load(bar, __ATOMIC_ACQUIRE, __HIP_MEMORY_SCOPE_AGENT) < target)
            __builtin_amdgcn_s_sleep(8);
        __threadfence();
    }
    __syncthreads();
}

#define ACC2(U)                                                              \
    {                                                                        \
        auto l0 = __builtin_amdgcn_cvt_pk_f32_fp8((int)(U).x, false);        \
        auto h0 = __builtin_amdgcn_cvt_pk_f32_fp8((int)(U).x, true);         \
        auto l1 = __builtin_amdgcn_cvt_pk_f32_fp8((int)(U).y, false);        \
        auto h1 = __builtin_amdgcn_cvt_pk_f32_fp8((int)(U).y, true);         \
        a0 += l0[0]; a1 += l0[1]; a2 += h0[0]; a3 += h0[1];                  \
        a4 += l1[0]; a5 += l1[1]; a6 += h1[0]; a7 += h1[1];                  \
    }

// ctl[0]=barrier ctl[1]=conv queue ctl[2]=bucket queue ctl[3]=tile queue
// ctl+4 = gcursor[NBK]
__global__ __launch_bounds__(BLK, 4) void mega_k(
        const int* __restrict__ ei, const float* __restrict__ x,
        const float* __restrict__ W, const float* __restrict__ Bm,
        int* __restrict__ ctl, unsigned int* __restrict__ xb,
        int* __restrict__ ebuf, unsigned short* __restrict__ psb,
        unsigned short* __restrict__ pcnt, float* __restrict__ out) {
    __shared__ __align__(16) unsigned char lds[69632];   // union; max = gemm Wt+Bt
    __shared__ int sh_id;
    const int t = threadIdx.x, lane = t & 63, wv = t >> 6;
    int* gcursor = ctl + 4;

    // ---------------- P1a: x (fp32) -> xb (packed fp8 e4m3 x4) --------------
    {
        const int total4 = NN * DD / 4;
        for (int i = blockIdx.x * BLK + t; i < total4; i += GRID * BLK) {
            float4 v = ((const float4*)x)[i];
            int p = __builtin_amdgcn_cvt_pk_fp8_f32(v.x, v.y, 0, false);
            p = __builtin_amdgcn_cvt_pk_fp8_f32(v.z, v.w, p, true);
            xb[i] = (unsigned)p;
        }
    }

    // ---------------- P1b: bucket-sorted edge scatter (chunk queue) ---------
    {
        int* c_stg = (int*)lds;               // [3584] (CHUNK padded)
        int* c_h   = c_stg + 3584;            // [NBK]
        int* c_lb  = c_h + NBK;
        int* c_gb  = c_lb + NBK;
        int* c_hc  = c_gb + NBK;
        int* c_ws  = c_hc + NBK;              // [8]
        int* c_wb  = c_ws + 8;                // [8]  (total 26.9 KB)
        for (;;) {
            if (t == 0) sh_id = atomicAdd(&ctl[1], 1);
            __syncthreads();
            const int c = sh_id;
            if (c >= NCH) break;
            const int e0 = c * CHUNK;
            const int ec = min(CHUNK, NE - e0);
            for (int i = t; i < NBK; i += BLK) c_h[i] = 0;
            __syncthreads();
            unsigned int w2[7];
            #pragma unroll
            for (int u = 0; u < 7; ++u) {
                int i = u * BLK + t;
                if (i < ec) {
                    int src = ei[e0 + i], dst = ei[NE + e0 + i];
                    int b = dst >> 6;
                    w2[u] = ((unsigned)b << 22) | ((unsigned)src << 6) | (unsigned)(dst & 63);
                    atomicAdd(&c_h[b], 1);
                } else w2[u] = 0xFFFFFFFFu;
            }
            __syncthreads();
            // pair scan over NBK = 2*391 buckets with 512 threads
            int va = 0, vb = 0, pv = 0;
            if (t < 391) { va = c_h[2 * t]; vb = c_h[2 * t + 1]; pv = va + vb; }
            int s = pv;
            #pragma unroll
            for (int o = 1; o < 64; o <<= 1) { int u = __shfl_up(s, o); if (lane >= o) s += u; }
            if (lane == 63) c_ws[wv] = s;
            __syncthreads();
            if (wv == 0 && lane < 8) {
                int bv = c_ws[lane], bs = bv;
                #pragma unroll
                for (int o = 1; o < 8; o <<= 1) { int u = __shfl_up(bs, o); if (lane >= o) bs += u; }
                c_wb[lane] = bs - bv;
            }
            __syncthreads();
            if (t < 391) {
                int excl = s - pv + c_wb[wv];
                c_lb[2 * t] = excl;          c_hc[2 * t] = excl;
                c_lb[2 * t + 1] = excl + va; c_hc[2 * t + 1] = excl + va;
                c_gb[2 * t]     = va ? (2 * t) * MAXB     + atomicAdd(&gcursor[2 * t], va)     : 0;
                c_gb[2 * t + 1] = vb ? (2 * t + 1) * MAXB + atomicAdd(&gcursor[2 * t + 1], vb) : 0;
            }
            __syncthreads();
            #pragma unroll
            for (int u = 0; u < 7; ++u) {
                if (w2[u] != 0xFFFFFFFFu) {
                    int b = w2[u] >> 22;
                    int pos = atomicAdd(&c_hc[b], 1);
                    c_stg[pos] = (int)w2[u];
                }
            }
            __syncthreads();
            for (int i = t; i < ec; i += BLK) {
                unsigned int w = (unsigned)c_stg[i];
                int b = w >> 22;
                ebuf[c_gb[b] + (i - c_lb[b])] = (int)(w & 0x3FFFFFu);
            }
            __syncthreads();
        }
    }
    gridbar(&ctl[0], GRID);

    // ---------------- P2: per-bucket node sort + fp8 gather (bucket queue) --
    {
        int* a_stg = (int*)lds;                                    // [MAXB]
        unsigned short* a_srt = (unsigned short*)(lds + MAXB * 4); // [MAXB]
        int* a_c8  = (int*)(lds + MAXB * 6);                       // [8][64]
        int* a_cur = a_c8 + 8 * 64;                                // [64]
        int* a_off = a_cur + 64;                                   // [65]
        const int sub = lane >> 4, il2 = lane & 15;
        for (;;) {
            if (t == 0) sh_id = atomicAdd(&ctl[2], 1);
            __syncthreads();
            const int b = sh_id;
            if (b >= NBK) break;
            const int n = min(gcursor[b], MAXB);
            const int* __restrict__ slab = ebuf + (size_t)b * MAXB;
            a_c8[wv * 64 + lane] = 0;
            for (int i = t; i < n; i += BLK) {
                int v = slab[i];
                a_stg[i] = v;
                atomicAdd(&a_c8[wv * 64 + (v & 63)], 1);
            }
            __syncthreads();
            if (t < 64) {
                int v = 0;
                #pragma unroll
                for (int w = 0; w < 8; ++w) v += a_c8[w * 64 + t];
                int s2 = v;
                #pragma unroll
                for (int o = 1; o < 64; o <<= 1) { int u = __shfl_up(s2, o); if (t >= o) s2 += u; }
                a_cur[t] = s2 - v; a_off[t] = s2 - v;
                if (t == 63) a_off[64] = s2;
            }
            __syncthreads();
            for (int i = t; i < n; i += BLK) {
                int w = a_stg[i];
                int pos = atomicAdd(&a_cur[w & 63], 1);
                a_srt[pos] = (unsigned short)(w >> 6);
            }
            __syncthreads();
            #pragma unroll
            for (int q = 0; q < 8; ++q) {
                int ln = wv + q * 8;
                int s0 = a_off[ln], s1 = a_off[ln + 1];
                float a0 = 0.f, a1 = 0.f, a2 = 0.f, a3 = 0.f;
                float a4 = 0.f, a5 = 0.f, a6 = 0.f, a7 = 0.f;
                int i = s0;
                for (; i + 16 <= s1; i += 16) {
                    uint2 u[4];
                    #pragma unroll
                    for (int k = 0; k < 4; ++k)
                        u[k] = ((const uint2*)xb)[(size_t)a_srt[i + 4 * k + sub] * 16 + il2];
                    #pragma unroll
                    for (int k = 0; k < 4; ++k) ACC2(u[k]);
                }
                if (i < s1) {
                    uint2 u[4];
                    #pragma unroll
                    for (int k = 0; k < 4; ++k) {
                        int e = i + 4 * k + sub;
                        if (e < s1) u[k] = ((const uint2*)xb)[(size_t)a_srt[e] * 16 + il2];
                        else { u[k].x = 0u; u[k].y = 0u; }
                    }
                    #pragma unroll
                    for (int k = 0; k < 4; ++k) ACC2(u[k]);
                }
                a0 += __shfl_xor(a0, 16); a0 += __shfl_xor(a0, 32);
                a1 += __shfl_xor(a1, 16); a1 += __shfl_xor(a1, 32);
                a2 += __shfl_xor(a2, 16); a2 += __shfl_xor(a2, 32);
                a3 += __shfl_xor(a3, 16); a3 += __shfl_xor(a3, 32);
                a4 += __shfl_xor(a4, 16); a4 += __shfl_xor(a4, 32);
                a5 += __shfl_xor(a5, 16); a5 += __shfl_xor(a5, 32);
                a6 += __shfl_xor(a6, 16); a6 += __shfl_xor(a6, 32);
                a7 += __shfl_xor(a7, 16); a7 += __shfl_xor(a7, 32);
                int node = b * NPB + ln;
                if (node < NN) {
                    if (lane < 16) {
                        short8 sv;
                        sv[0] = (short)to_bf16(a0); sv[1] = (short)to_bf16(a1);
                        sv[2] = (short)to_bf16(a2); sv[3] = (short)to_bf16(a3);
                        sv[4] = (short)to_bf16(a4); sv[5] = (short)to_bf16(a5);
                        sv[6] = (short)to_bf16(a6); sv[7] = (short)to_bf16(a7);
                        *(short8*)&psb[(size_t)node * DD + il2 * 8] = sv;
                    }
                    if (lane == 0) pcnt[node] = (unsigned short)(s1 - s0);
                }
            }
            __syncthreads();
        }
    }
    gridbar(&ctl[0], 2 * GRID);

    // ---------------- P3: MFMA epilogue (tile queue) ------------------------
    {
        unsigned short* Wt = (unsigned short*)lds;       // [DD*WS]
        unsigned short* Bt = Wt + DD * WS;               // [DD*WS]  (69.6 KB)
        #pragma unroll
        for (int it = 0; it < 8; ++it) {
            int idx = it * BLK + t;                      // 4096 ushort4 per matrix
            int nrow = idx >> 5, k0 = (idx & 31) * 4;
            float4 w4 = ((const float4*)W)[idx];
            float4 b4 = ((const float4*)Bm)[idx];
            ushort4 wp, bp;
            wp.x = to_bf16(w4.x); wp.y = to_bf16(w4.y); wp.z = to_bf16(w4.z); wp.w = to_bf16(w4.w);
            bp.x = to_bf16(b4.x); bp.y = to_bf16(b4.y); bp.z = to_bf16(b4.z); bp.w = to_bf16(b4.w);
            *(ushort4*)&Wt[nrow * WS + k0] = wp;
            *(ushort4*)&Bt[nrow * WS + k0] = bp;
        }
        __syncthreads();
        const int m = lane & 15, quad = lane >> 4;
        for (;;) {
            if (t == 0) sh_id = atomicAdd(&ctl[3], 1);
            __syncthreads();
            const int tile = sh_id;
            if (tile >= NT) break;
            const int rowA = min(tile * 128 + wv * 16 + m, NN - 1);
            const float deg = (float)pcnt[rowA];
            const float inv = 1.0f / fmaxf(deg, 1.0f);
            f32x4 acc[8];
            #pragma unroll
            for (int nt = 0; nt < 8; ++nt) acc[nt] = (f32x4){0.f, 0.f, 0.f, 0.f};
            #pragma unroll
            for (int tt = 0; tt < 4; ++tt) {
                const int k8 = tt * 32 + quad * 8;
                short8 p0 = *(const short8*)&psb[(size_t)rowA * DD + k8];
                short8 mf;
                #pragma unroll
                for (int j = 0; j < 8; ++j)
                    mf[j] = (short)to_bf16(bf2f((unsigned short)p0[j]) * inv);
                float xv[8];
                {
                    const float4* xq = (const float4*)&x[(size_t)rowA * DD + k8];
                    float4 b0 = xq[0], b1 = xq[1];
                    xv[0] = b0.x; xv[1] = b0.y; xv[2] = b0.z; xv[3] = b0.w;
                    xv[4] = b1.x; xv[5] = b1.y; xv[6] = b1.z; xv[7] = b1.w;
                }
                short8 xh, xl;
                #pragma unroll
                for (int j = 0; j < 8; ++j) {
                    unsigned short g = to_bf16(xv[j]);
                    xh[j] = (short)g;
                    xl[j] = (short)to_bf16(xv[j] - __uint_as_float((unsigned)g << 16));
                }
                #pragma unroll
                for (int nt = 0; nt < 8; ++nt) {
                    int nrow = nt * 16 + m;
                    short8 wf = *(const short8*)&Wt[nrow * WS + k8];
                    short8 bf = *(const short8*)&Bt[nrow * WS + k8];
                    acc[nt] = __builtin_amdgcn_mfma_f32_16x16x32_bf16(xl, bf, acc[nt], 0, 0, 0);
                    acc[nt] = __builtin_amdgcn_mfma_f32_16x16x32_bf16(mf, wf, acc[nt], 0, 0, 0);
                    acc[nt] = __builtin_amdgcn_mfma_f32_16x16x32_bf16(xh, bf, acc[nt], 0, 0, 0);
                }
            }
            // C/D layout: col = lane&15, row = quad*4 + reg (verified m89/m91)
            const int rowD0 = tile * 128 + wv * 16 + quad * 4;
            #pragma unroll
            for (int nt = 0; nt < 8; ++nt) {
                #pragma unroll
                for (int r = 0; r < 4; ++r) {
                    int row = rowD0 + r;
                    if (row < NN) out[(size_t)row * DD + nt * 16 + m] = acc[nt][r];
                }
            }
            __syncthreads();   // protect sh_id before next pop
        }
    }
}

extern "C" void kernel_launch(void* const* d_in, const int* in_sizes, int n_in,
                              void* d_out, int out_size, void* d_ws, size_t ws_size,
                              hipStream_t stream) {
    const float* x  = (const float*)d_in[0];
    const int*   ei = (const int*)d_in[1];   // [2, NE] int32
    const float* W  = (const float*)d_in[2];
    const float* Bm = (const float*)d_in[3];
    float* out = (float*)d_out;

    int* ctl             = (int*)d_ws;                           // 1024 ints reserved
    unsigned int* xb     = (unsigned int*)d_ws + 1024;           // NN*32 uints (6.4 MB)
    int* ebuf            = (int*)(xb + (size_t)NN * 32);         // NBK*MAXB ints (8 MB)
    unsigned short* psb  = (unsigned short*)(ebuf + (size_t)NBK * MAXB); // NN*DD bf16
    unsigned short* pcnt = psb + (size_t)NN * DD;                // NN u16

    hipMemsetAsync(ctl, 0, (4 + NBK) * sizeof(int), stream);     // bar+queues+gcursor
    mega_k<<<GRID, BLK, 0, stream>>>(ei, x, W, Bm, ctl, xb, ebuf, psb, pcnt, out);
}

// Round 9
// 268.199 us; speedup vs baseline: 1.4290x; 1.4290x over previous
//
#include <hip/hip_runtime.h>
#include <hip/hip_bf16.h>

#define NN 50000
#define NE 1600000
#define DD 128
#define NPB 64                 // nodes per bucket (dst>>6)
#define NBK 782                // ceil(NN/64)
#define MAXB 2560              // bucket slab capacity (mean 2048, +11 sigma)
#define GRID 448               // < guaranteed co-resident capacity (2/CU x 256 = 512)
#define BLK 512
#define CHUNK 3572             // ceil(NE/GRID): one balanced conv round
#define NCH 448
#define NT 391                 // gemm tiles of 128 rows
#define WS 136                 // gemm LDS row stride (bf16): balanced banks

typedef __attribute__((ext_vector_type(8))) short short8;
typedef __attribute__((ext_vector_type(4))) float f32x4;

__device__ inline unsigned short to_bf16(float v) {
    __hip_bfloat16 h = __float2bfloat16(v);
    return __builtin_bit_cast(unsigned short, h);
}
__device__ inline float bf2f(unsigned short u) {
    return __uint_as_float((unsigned)u << 16);
}

// Device-scope grid barrier, invalidation-safe spin.
// Round-8 lesson: an ACQUIRE agent-scope load PER SPIN ITERATION forces an
// L1(+XCD-L2) invalidate each time; 448 spinners -> cache-invalidation storm
// that collapsed the whole kernel to 6% HBM / 5% VALU. Fix: RELAXED atomic
// spin (atomics are scope-coherent regardless of ordering -> no deadlock,
// no invalidates), then ONE __threadfence() acquire after the condition.
__device__ inline void gridbar(int* bar, int target) {
    __syncthreads();
    if (threadIdx.x == 0) {
        __threadfence();   // release: make this block's writes agent-visible
        __hip_atomic_fetch_add(bar, 1, __ATOMIC_RELAXED, __HIP_MEMORY_SCOPE_AGENT);
        while (__hip_atomic_load(bar, __ATOMIC_RELAXED, __HIP_MEMORY_SCOPE_AGENT) < target)
            __builtin_amdgcn_s_sleep(8);
        __threadfence();   // acquire: invalidate stale cache ONCE
    }
    __syncthreads();
}

#define ACC2(U)                                                              \
    {                                                                        \
        auto l0 = __builtin_amdgcn_cvt_pk_f32_fp8((int)(U).x, false);        \
        auto h0 = __builtin_amdgcn_cvt_pk_f32_fp8((int)(U).x, true);         \
        auto l1 = __builtin_amdgcn_cvt_pk_f32_fp8((int)(U).y, false);        \
        auto h1 = __builtin_amdgcn_cvt_pk_f32_fp8((int)(U).y, true);         \
        a0 += l0[0]; a1 += l0[1]; a2 += h0[0]; a3 += h0[1];                  \
        a4 += l1[0]; a5 += l1[1]; a6 += h1[0]; a7 += h1[1];                  \
    }

// ctl[0]=barrier  ctl[16]=conv queue  ctl[32]=bucket queue  ctl[48]=tile queue
// (line-padded so spinners and queue poppers never share a cache line)
// ctl+64 = gcursor[NBK]
__global__ __launch_bounds__(BLK, 4) void mega_k(
        const int* __restrict__ ei, const float* __restrict__ x,
        const float* __restrict__ W, const float* __restrict__ Bm,
        int* __restrict__ ctl, unsigned int* __restrict__ xb,
        int* __restrict__ ebuf, unsigned short* __restrict__ psb,
        unsigned short* __restrict__ pcnt, unsigned short* __restrict__ Wbf,
        unsigned short* __restrict__ Bbf, float* __restrict__ out) {
    __shared__ __align__(16) unsigned char lds[69632];   // union; max = gemm Wt+Bt
    __shared__ int sh_id;
    const int t = threadIdx.x, lane = t & 63, wv = t >> 6;
    int* gcursor = ctl + 64;

    // ---------------- P1a: x (fp32) -> xb (packed fp8 e4m3 x4) --------------
    {
        const int total4 = NN * DD / 4;
        for (int i = blockIdx.x * BLK + t; i < total4; i += GRID * BLK) {
            float4 v = ((const float4*)x)[i];
            int p = __builtin_amdgcn_cvt_pk_fp8_f32(v.x, v.y, 0, false);
            p = __builtin_amdgcn_cvt_pk_fp8_f32(v.z, v.w, p, true);
            xb[i] = (unsigned)p;
        }
    }
    // W,B fp32 -> bf16 once (last block; consumed by P3 after 2 barriers)
    if (blockIdx.x == GRID - 1) {
        for (int i = t; i < DD * DD / 4; i += BLK) {
            float4 w4 = ((const float4*)W)[i];
            float4 b4 = ((const float4*)Bm)[i];
            ushort4 wp, bp;
            wp.x = to_bf16(w4.x); wp.y = to_bf16(w4.y); wp.z = to_bf16(w4.z); wp.w = to_bf16(w4.w);
            bp.x = to_bf16(b4.x); bp.y = to_bf16(b4.y); bp.z = to_bf16(b4.z); bp.w = to_bf16(b4.w);
            ((ushort4*)Wbf)[i] = wp;
            ((ushort4*)Bbf)[i] = bp;
        }
    }

    // ---------------- P1b: bucket-sorted edge scatter (chunk queue) ---------
    {
        int* c_stg = (int*)lds;               // [3584] (CHUNK padded)
        int* c_h   = c_stg + 3584;            // [NBK]
        int* c_lb  = c_h + NBK;
        int* c_gb  = c_lb + NBK;
        int* c_hc  = c_gb + NBK;
        int* c_ws  = c_hc + NBK;              // [8]
        int* c_wb  = c_ws + 8;                // [8]  (total 26.9 KB)
        for (;;) {
            if (t == 0) sh_id = atomicAdd(&ctl[16], 1);
            __syncthreads();
            const int c = sh_id;
            if (c >= NCH) break;
            const int e0 = c * CHUNK;
            const int ec = min(CHUNK, NE - e0);
            for (int i = t; i < NBK; i += BLK) c_h[i] = 0;
            __syncthreads();
            unsigned int w2[7];
            #pragma unroll
            for (int u = 0; u < 7; ++u) {
                int i = u * BLK + t;
                if (i < ec) {
                    int src = ei[e0 + i], dst = ei[NE + e0 + i];
                    int b = dst >> 6;
                    w2[u] = ((unsigned)b << 22) | ((unsigned)src << 6) | (unsigned)(dst & 63);
                    atomicAdd(&c_h[b], 1);
                } else w2[u] = 0xFFFFFFFFu;
            }
            __syncthreads();
            // pair scan over NBK = 2*391 buckets with 512 threads
            int va = 0, vb = 0, pv = 0;
            if (t < 391) { va = c_h[2 * t]; vb = c_h[2 * t + 1]; pv = va + vb; }
            int s = pv;
            #pragma unroll
            for (int o = 1; o < 64; o <<= 1) { int u = __shfl_up(s, o); if (lane >= o) s += u; }
            if (lane == 63) c_ws[wv] = s;
            __syncthreads();
            if (wv == 0 && lane < 8) {
                int bv = c_ws[lane], bs = bv;
                #pragma unroll
                for (int o = 1; o < 8; o <<= 1) { int u = __shfl_up(bs, o); if (lane >= o) bs += u; }
                c_wb[lane] = bs - bv;
            }
            __syncthreads();
            if (t < 391) {
                int excl = s - pv + c_wb[wv];
                c_lb[2 * t] = excl;          c_hc[2 * t] = excl;
                c_lb[2 * t + 1] = excl + va; c_hc[2 * t + 1] = excl + va;
                c_gb[2 * t]     = va ? (2 * t) * MAXB     + atomicAdd(&gcursor[2 * t], va)     : 0;
                c_gb[2 * t + 1] = vb ? (2 * t + 1) * MAXB + atomicAdd(&gcursor[2 * t + 1], vb) : 0;
            }
            __syncthreads();
            #pragma unroll
            for (int u = 0; u < 7; ++u) {
                if (w2[u] != 0xFFFFFFFFu) {
                    int b = w2[u] >> 22;
                    int pos = atomicAdd(&c_hc[b], 1);
                    c_stg[pos] = (int)w2[u];
                }
            }
            __syncthreads();
            for (int i = t; i < ec; i += BLK) {
                unsigned int w = (unsigned)c_stg[i];
                int b = w >> 22;
                ebuf[c_gb[b] + (i - c_lb[b])] = (int)(w & 0x3FFFFFu);
            }
            __syncthreads();
        }
    }
    gridbar(&ctl[0], GRID);

    // ---------------- P2: per-bucket node sort + fp8 gather (bucket queue) --
    {
        int* a_stg = (int*)lds;                                    // [MAXB]
        unsigned short* a_srt = (unsigned short*)(lds + MAXB * 4); // [MAXB]
        int* a_c8  = (int*)(lds + MAXB * 6);                       // [8][64]
        int* a_cur = a_c8 + 8 * 64;                                // [64]
        int* a_off = a_cur + 64;                                   // [65]
        const int sub = lane >> 4, il2 = lane & 15;
        for (;;) {
            if (t == 0) sh_id = atomicAdd(&ctl[32], 1);
            __syncthreads();
            const int b = sh_id;
            if (b >= NBK) break;
            const int n = min(gcursor[b], MAXB);
            const int* __restrict__ slab = ebuf + (size_t)b * MAXB;
            a_c8[wv * 64 + lane] = 0;
            for (int i = t; i < n; i += BLK) {
                int v = slab[i];
                a_stg[i] = v;
                atomicAdd(&a_c8[wv * 64 + (v & 63)], 1);
            }
            __syncthreads();
            if (t < 64) {
                int v = 0;
                #pragma unroll
                for (int w = 0; w < 8; ++w) v += a_c8[w * 64 + t];
                int s2 = v;
                #pragma unroll
                for (int o = 1; o < 64; o <<= 1) { int u = __shfl_up(s2, o); if (t >= o) s2 += u; }
                a_cur[t] = s2 - v; a_off[t] = s2 - v;
                if (t == 63) a_off[64] = s2;
            }
            __syncthreads();
            for (int i = t; i < n; i += BLK) {
                int w = a_stg[i];
                int pos = atomicAdd(&a_cur[w & 63], 1);
                a_srt[pos] = (unsigned short)(w >> 6);
            }
            __syncthreads();
            #pragma unroll
            for (int q = 0; q < 8; ++q) {
                int ln = wv + q * 8;
                int s0 = a_off[ln], s1 = a_off[ln + 1];
                float a0 = 0.f, a1 = 0.f, a2 = 0.f, a3 = 0.f;
                float a4 = 0.f, a5 = 0.f, a6 = 0.f, a7 = 0.f;
                int i = s0;
                for (; i + 16 <= s1; i += 16) {
                    uint2 u[4];
                    #pragma unroll
                    for (int k = 0; k < 4; ++k)
                        u[k] = ((const uint2*)xb)[(size_t)a_srt[i + 4 * k + sub] * 16 + il2];
                    #pragma unroll
                    for (int k = 0; k < 4; ++k) ACC2(u[k]);
                }
                if (i < s1) {
                    uint2 u[4];
                    #pragma unroll
                    for (int k = 0; k < 4; ++k) {
                        int e = i + 4 * k + sub;
                        if (e < s1) u[k] = ((const uint2*)xb)[(size_t)a_srt[e] * 16 + il2];
                        else { u[k].x = 0u; u[k].y = 0u; }
                    }
                    #pragma unroll
                    for (int k = 0; k < 4; ++k) ACC2(u[k]);
                }
                a0 += __shfl_xor(a0, 16); a0 += __shfl_xor(a0, 32);
                a1 += __shfl_xor(a1, 16); a1 += __shfl_xor(a1, 32);
                a2 += __shfl_xor(a2, 16); a2 += __shfl_xor(a2, 32);
                a3 += __shfl_xor(a3, 16); a3 += __shfl_xor(a3, 32);
                a4 += __shfl_xor(a4, 16); a4 += __shfl_xor(a4, 32);
                a5 += __shfl_xor(a5, 16); a5 += __shfl_xor(a5, 32);
                a6 += __shfl_xor(a6, 16); a6 += __shfl_xor(a6, 32);
                a7 += __shfl_xor(a7, 16); a7 += __shfl_xor(a7, 32);
                int node = b * NPB + ln;
                if (node < NN) {
                    if (lane < 16) {
                        short8 sv;
                        sv[0] = (short)to_bf16(a0); sv[1] = (short)to_bf16(a1);
                        sv[2] = (short)to_bf16(a2); sv[3] = (short)to_bf16(a3);
                        sv[4] = (short)to_bf16(a4); sv[5] = (short)to_bf16(a5);
                        sv[6] = (short)to_bf16(a6); sv[7] = (short)to_bf16(a7);
                        *(short8*)&psb[(size_t)node * DD + il2 * 8] = sv;
                    }
                    if (lane == 0) pcnt[node] = (unsigned short)(s1 - s0);
                }
            }
            __syncthreads();
        }
    }
    gridbar(&ctl[0], 2 * GRID);

    // ---------------- P3: MFMA epilogue (tile queue) ------------------------
    {
        unsigned short* Wt = (unsigned short*)lds;       // [DD*WS]
        unsigned short* Bt = Wt + DD * WS;               // [DD*WS]  (69.6 KB)
        #pragma unroll
        for (int it = 0; it < 8; ++it) {
            int idx = it * BLK + t;                      // 4096 ushort4 per matrix
            int nrow = idx >> 5, k0 = (idx & 31) * 4;
            *(ushort4*)&Wt[nrow * WS + k0] = ((const ushort4*)Wbf)[idx];
            *(ushort4*)&Bt[nrow * WS + k0] = ((const ushort4*)Bbf)[idx];
        }
        __syncthreads();
        const int m = lane & 15, quad = lane >> 4;
        for (;;) {
            if (t == 0) sh_id = atomicAdd(&ctl[48], 1);
            __syncthreads();
            const int tile = sh_id;
            if (tile >= NT) break;
            const int rowA = min(tile * 128 + wv * 16 + m, NN - 1);
            const float deg = (float)pcnt[rowA];
            const float inv = 1.0f / fmaxf(deg, 1.0f);
            f32x4 acc[8];
            #pragma unroll
            for (int nt = 0; nt < 8; ++nt) acc[nt] = (f32x4){0.f, 0.f, 0.f, 0.f};
            #pragma unroll
            for (int tt = 0; tt < 4; ++tt) {
                const int k8 = tt * 32 + quad * 8;
                short8 p0 = *(const short8*)&psb[(size_t)rowA * DD + k8];
                short8 mf;
                #pragma unroll
                for (int j = 0; j < 8; ++j)
                    mf[j] = (short)to_bf16(bf2f((unsigned short)p0[j]) * inv);
                float xv[8];
                {
                    const float4* xq = (const float4*)&x[(size_t)rowA * DD + k8];
                    float4 b0 = xq[0], b1 = xq[1];
                    xv[0] = b0.x; xv[1] = b0.y; xv[2] = b0.z; xv[3] = b0.w;
                    xv[4] = b1.x; xv[5] = b1.y; xv[6] = b1.z; xv[7] = b1.w;
                }
                short8 xh, xl;
                #pragma unroll
                for (int j = 0; j < 8; ++j) {
                    unsigned short g = to_bf16(xv[j]);
                    xh[j] = (short)g;
                    xl[j] = (short)to_bf16(xv[j] - __uint_as_float((unsigned)g << 16));
                }
                #pragma unroll
                for (int nt = 0; nt < 8; ++nt) {
                    int nrow = nt * 16 + m;
                    short8 wf = *(const short8*)&Wt[nrow * WS + k8];
                    short8 bf = *(const short8*)&Bt[nrow * WS + k8];
                    acc[nt] = __builtin_amdgcn_mfma_f32_16x16x32_bf16(xl, bf, acc[nt], 0, 0, 0);
                    acc[nt] = __builtin_amdgcn_mfma_f32_16x16x32_bf16(mf, wf, acc[nt], 0, 0, 0);
                    acc[nt] = __builtin_amdgcn_mfma_f32_16x16x32_bf16(xh, bf, acc[nt], 0, 0, 0);
                }
            }
            // C/D layout: col = lane&15, row = quad*4 + reg (verified m89/m91)
            const int rowD0 = tile * 128 + wv * 16 + quad * 4;
            #pragma unroll
            for (int nt = 0; nt < 8; ++nt) {
                #pragma unroll
                for (int r = 0; r < 4; ++r) {
                    int row = rowD0 + r;
                    if (row < NN) out[(size_t)row * DD + nt * 16 + m] = acc[nt][r];
                }
            }
            __syncthreads();   // protect sh_id before next pop
        }
    }
}

extern "C" void kernel_launch(void* const* d_in, const int* in_sizes, int n_in,
                              void* d_out, int out_size, void* d_ws, size_t ws_size,
                              hipStream_t stream) {
    const float* x  = (const float*)d_in[0];
    const int*   ei = (const int*)d_in[1];   // [2, NE] int32
    const float* W  = (const float*)d_in[2];
    const float* Bm = (const float*)d_in[3];
    float* out = (float*)d_out;

    int* ctl             = (int*)d_ws;                           // 2048 ints reserved
    unsigned int* xb     = (unsigned int*)d_ws + 2048;           // NN*32 uints (6.4 MB)
    int* ebuf            = (int*)(xb + (size_t)NN * 32);         // NBK*MAXB ints (8 MB)
    unsigned short* psb  = (unsigned short*)(ebuf + (size_t)NBK * MAXB); // NN*DD bf16
    unsigned short* pcnt = psb + (size_t)NN * DD;                // NN u16
    unsigned short* Wbf  = pcnt + (size_t)NN;                    // DD*DD bf16
    unsigned short* Bbf  = Wbf + DD * DD;                        // DD*DD bf16

    hipMemsetAsync(ctl, 0, (64 + NBK) * sizeof(int), stream);    // bar+queues+gcursor
    mega_k<<<GRID, BLK, 0, stream>>>(ei, x, W, Bm, ctl, xb, ebuf, psb, pcnt, Wbf, Bbf, out);
}

// Round 10
// 177.936 us; speedup vs baseline: 2.1540x; 1.5073x over previous
//
#include <hip/hip_runtime.h>
#include <hip/hip_bf16.h>

#define NN 50000
#define NE 1600000
#define DD 128
#define NPB 64                 // nodes per bucket (dst>>6)
#define NBK 782                // ceil(NN/64)
#define MAXB 2560              // bucket slab capacity (mean 2048, +11 sigma)
#define CHUNK 3072             // edges per convscatter block (2 blocks/CU shape)
#define NCB 521                // ceil(NE/CHUNK)
#define MWS 136                // meanL LDS row stride (bf16): balanced banks

typedef __attribute__((ext_vector_type(8))) short short8;
typedef __attribute__((ext_vector_type(4))) float f32x4;

__device__ inline unsigned short to_bf16(float v) {
    __hip_bfloat16 h = __float2bfloat16(v);
    return __builtin_bit_cast(unsigned short, h);
}

// ---- phase 1: x->fp8 convert + W/B->bf16 convert + bucket-sorted scatter ----
// Round-7 verified form (154.4 us run): 521 blocks x 1024 thr.
__global__ __launch_bounds__(1024) void convscatter_k(const int* __restrict__ ei,
                                                      const float* __restrict__ x,
                                                      const float* __restrict__ W,
                                                      const float* __restrict__ Bm,
                                                      unsigned int* __restrict__ xb,
                                                      unsigned short* __restrict__ Wbf,
                                                      unsigned short* __restrict__ Bbf,
                                                      int* __restrict__ gcursor,
                                                      int* __restrict__ ebuf) {
    __shared__ int stg[CHUNK];        // 12 KB
    __shared__ int h[NBK];
    __shared__ int lbase[NBK];
    __shared__ int gb[NBK];
    __shared__ int hcur[NBK];
    __shared__ int wsum[16], wbase[16];
    const int t = threadIdx.x;
    const int lane = t & 63, wv = t >> 6;
    const int e0 = blockIdx.x * CHUNK;
    const int ec = min(CHUNK, NE - e0);

    for (int i = t; i < NBK; i += 1024) h[i] = 0;
    __syncthreads();

    unsigned int w2[3];
    #pragma unroll
    for (int u = 0; u < 3; ++u) {
        int i = u * 1024 + t;
        if (i < ec) {
            int src = ei[e0 + i];
            int dst = ei[NE + e0 + i];
            int b = dst >> 6;
            w2[u] = ((unsigned)b << 22) | ((unsigned)src << 6) | (unsigned)(dst & 63);
            atomicAdd(&h[b], 1);
        } else w2[u] = 0xFFFFFFFFu;
    }

    // independent: convert x (fp32) -> xb (packed 4x fp8-e4m3 per uint)
    {
        int gid = blockIdx.x * 1024 + t;
        const int total4 = NN * DD / 4;  // 1.6M float4 -> 1.6M uints
        for (int i = gid; i < total4; i += NCB * 1024) {
            float4 v = ((const float4*)x)[i];
            int p = __builtin_amdgcn_cvt_pk_fp8_f32(v.x, v.y, 0, false);
            p = __builtin_amdgcn_cvt_pk_fp8_f32(v.z, v.w, p, true);
            xb[i] = (unsigned)p;
        }
    }
    // independent: convert W,B (fp32) -> bf16, done by the underloaded last block
    if (blockIdx.x == NCB - 1) {
        for (int i = t; i < DD * DD / 4; i += 1024) {
            float4 w4 = ((const float4*)W)[i];
            float4 b4 = ((const float4*)Bm)[i];
            ushort4 wp, bp;
            wp.x = to_bf16(w4.x); wp.y = to_bf16(w4.y); wp.z = to_bf16(w4.z); wp.w = to_bf16(w4.w);
            bp.x = to_bf16(b4.x); bp.y = to_bf16(b4.y); bp.z = to_bf16(b4.z); bp.w = to_bf16(b4.w);
            ((ushort4*)Wbf)[i] = wp;
            ((ushort4*)Bbf)[i] = bp;
        }
    }
    __syncthreads();

    // hierarchical scan over NBK buckets (1 per thread, 2 barriers)
    int v = (t < NBK) ? h[t] : 0;
    int s = v;
    #pragma unroll
    for (int o = 1; o < 64; o <<= 1) {
        int u = __shfl_up(s, o);
        if (lane >= o) s += u;
    }
    if (lane == 63) wsum[wv] = s;
    __syncthreads();
    if (wv == 0 && lane < 16) {
        int bv = wsum[lane];
        int bs = bv;
        #pragma unroll
        for (int o = 1; o < 16; o <<= 1) {
            int u = __shfl_up(bs, o);
            if (lane >= o) bs += u;
        }
        wbase[lane] = bs - bv;
    }
    __syncthreads();
    if (t < NBK) {
        int excl = s - v + wbase[wv];
        lbase[t] = excl;
        hcur[t] = excl;
        gb[t] = v ? t * MAXB + atomicAdd(&gcursor[t], v) : 0;
    }
    __syncthreads();

    // LDS counting sort of the chunk by bucket
    #pragma unroll
    for (int u = 0; u < 3; ++u) {
        if (w2[u] != 0xFFFFFFFFu) {
            int b = w2[u] >> 22;
            int pos = atomicAdd(&hcur[b], 1);
            stg[pos] = (int)w2[u];
        }
    }
    __syncthreads();

    // coalesced global write in sorted order
    for (int i = t; i < ec; i += 1024) {
        unsigned int w = (unsigned)stg[i];
        int b = w >> 22;
        ebuf[gb[b] + (i - lbase[b])] = (int)(w & 0x3FFFFFu);
    }
}

// ---- phase 2+3 fused: sort + fp8 gather (32 waves/CU) + MFMA for 64 rows ----
// One 1024-thr block per bucket. Gather phase identical to round-7 sortagg
// (best measured shape); mean stays in LDS (17.4 KB) -> no psb/pcnt globals,
// one less dispatch, one less bf16 rounding. GEMM phase: 16 waves x 2 col-
// tiles, W/B fragments read directly from L2-hot bf16 copies (no LDS staging
// so total LDS = 37 KB keeps 2 blocks/CU for the gather).
#define ACC2(U)                                                              \
    {                                                                        \
        auto l0 = __builtin_amdgcn_cvt_pk_f32_fp8((int)(U).x, false);        \
        auto h0 = __builtin_amdgcn_cvt_pk_f32_fp8((int)(U).x, true);         \
        auto l1 = __builtin_amdgcn_cvt_pk_f32_fp8((int)(U).y, false);        \
        auto h1 = __builtin_amdgcn_cvt_pk_f32_fp8((int)(U).y, true);         \
        a0 += l0[0]; a1 += l0[1]; a2 += h0[0]; a3 += h0[1];                  \
        a4 += l1[0]; a5 += l1[1]; a6 += h1[0]; a7 += h1[1];                  \
    }

__global__ __launch_bounds__(1024, 8) void aggemm_k(const unsigned int* __restrict__ xb,
                                                    const int* __restrict__ ebuf,
                                                    const int* __restrict__ gcursor,
                                                    const unsigned short* __restrict__ Wbf,
                                                    const unsigned short* __restrict__ Bbf,
                                                    const float* __restrict__ x,
                                                    float* __restrict__ out) {
    __shared__ int stg[MAXB];                    // 10.2 KB
    __shared__ unsigned short srt[MAXB];         // 5.1 KB
    __shared__ int cnt16[16][NPB];               // 4 KB (wave-private)
    __shared__ int cur[NPB], off[NPB + 1];
    __shared__ unsigned short meanL[NPB * MWS];  // 17.4 KB
    const int b = blockIdx.x, t = threadIdx.x;
    const int wv = t >> 6, lane = t & 63;
    const int n = min(gcursor[b], MAXB);
    const int* __restrict__ slab = ebuf + (size_t)b * MAXB;

    // stage slab + wave-private histogram in one pass
    cnt16[wv][lane] = 0;
    for (int i = t; i < n; i += 1024) {
        int v = slab[i];
        stg[i] = v;
        atomicAdd(&cnt16[wv][v & 63], 1);
    }
    __syncthreads();
    if (t < 64) {
        int v = 0;
        #pragma unroll
        for (int w = 0; w < 16; ++w) v += cnt16[w][t];
        int s = v;
        #pragma unroll
        for (int o = 1; o < 64; o <<= 1) {
            int u = __shfl_up(s, o);
            if (t >= o) s += u;
        }
        cur[t] = s - v;
        off[t] = s - v;
        if (t == 63) off[64] = s;
    }
    __syncthreads();
    for (int i = t; i < n; i += 1024) {
        int w = stg[i];
        int pos = atomicAdd(&cur[w & 63], 1);
        srt[pos] = (unsigned short)(w >> 6);
    }
    __syncthreads();

    // gather + mean -> LDS: uint2 per lane (16 lanes per edge-row)
    const int sub = lane >> 4, il2 = lane & 15;
    #pragma unroll
    for (int q = 0; q < 4; ++q) {
        int ln = wv + q * 16;                // interleaved for degree balance
        int s0 = off[ln], s1 = off[ln + 1];
        float a0 = 0.f, a1 = 0.f, a2 = 0.f, a3 = 0.f;
        float a4 = 0.f, a5 = 0.f, a6 = 0.f, a7 = 0.f;
        int i = s0;
        for (; i + 16 <= s1; i += 16) {      // 4 uint2 in flight = 16 edges
            uint2 u[4];
            #pragma unroll
            for (int k = 0; k < 4; ++k)
                u[k] = ((const uint2*)xb)[(size_t)srt[i + 4 * k + sub] * 16 + il2];
            #pragma unroll
            for (int k = 0; k < 4; ++k) ACC2(u[k]);
        }
        if (i < s1) {                        // batched predicated tail (<=15 edges)
            uint2 u[4];
            #pragma unroll
            for (int k = 0; k < 4; ++k) {
                int e = i + 4 * k + sub;
                if (e < s1) u[k] = ((const uint2*)xb)[(size_t)srt[e] * 16 + il2];
                else { u[k].x = 0u; u[k].y = 0u; }
            }
            #pragma unroll
            for (int k = 0; k < 4; ++k) ACC2(u[k]);
        }
        a0 += __shfl_xor(a0, 16); a0 += __shfl_xor(a0, 32);
        a1 += __shfl_xor(a1, 16); a1 += __shfl_xor(a1, 32);
        a2 += __shfl_xor(a2, 16); a2 += __shfl_xor(a2, 32);
        a3 += __shfl_xor(a3, 16); a3 += __shfl_xor(a3, 32);
        a4 += __shfl_xor(a4, 16); a4 += __shfl_xor(a4, 32);
        a5 += __shfl_xor(a5, 16); a5 += __shfl_xor(a5, 32);
        a6 += __shfl_xor(a6, 16); a6 += __shfl_xor(a6, 32);
        a7 += __shfl_xor(a7, 16); a7 += __shfl_xor(a7, 32);
        if (lane < 16) {
            float inv = 1.0f / fmaxf((float)(s1 - s0), 1.0f);
            short8 sv;
            sv[0] = (short)to_bf16(a0 * inv); sv[1] = (short)to_bf16(a1 * inv);
            sv[2] = (short)to_bf16(a2 * inv); sv[3] = (short)to_bf16(a3 * inv);
            sv[4] = (short)to_bf16(a4 * inv); sv[5] = (short)to_bf16(a5 * inv);
            sv[6] = (short)to_bf16(a6 * inv); sv[7] = (short)to_bf16(a7 * inv);
            *(short8*)&meanL[ln * MWS + il2 * 8] = sv;
        }
    }
    __syncthreads();

    // ---- MFMA epilogue: 16 waves = 4 row-tiles x 4 col-groups (2 tiles each)
    const int m = lane & 15, quad = lane >> 4;
    const int rt = wv & 3, cg = wv >> 2;
    const int rowLoc = rt * 16 + m;
    const int rowA = min(b * 64 + rowLoc, NN - 1);

    f32x4 acc[2];
    acc[0] = (f32x4){0.f, 0.f, 0.f, 0.f};
    acc[1] = (f32x4){0.f, 0.f, 0.f, 0.f};

    #pragma unroll
    for (int tt = 0; tt < 4; ++tt) {
        const int k8 = tt * 32 + quad * 8;
        short8 mf = *(const short8*)&meanL[rowLoc * MWS + k8];
        float xv[8];
        {
            const float4* xq = (const float4*)&x[(size_t)rowA * DD + k8];
            float4 b0 = xq[0], b1 = xq[1];
            xv[0] = b0.x; xv[1] = b0.y; xv[2] = b0.z; xv[3] = b0.w;
            xv[4] = b1.x; xv[5] = b1.y; xv[6] = b1.z; xv[7] = b1.w;
        }
        short8 xh, xl;
        #pragma unroll
        for (int j = 0; j < 8; ++j) {
            unsigned short g = to_bf16(xv[j]);
            xh[j] = (short)g;
            xl[j] = (short)to_bf16(xv[j] - __uint_as_float((unsigned)g << 16));
        }
        #pragma unroll
        for (int j = 0; j < 2; ++j) {
            int nrow = (cg * 2 + j) * 16 + m;
            short8 wf = *(const short8*)&Wbf[(size_t)nrow * DD + k8];
            short8 bf = *(const short8*)&Bbf[(size_t)nrow * DD + k8];
            acc[j] = __builtin_amdgcn_mfma_f32_16x16x32_bf16(xl, bf, acc[j], 0, 0, 0);
            acc[j] = __builtin_amdgcn_mfma_f32_16x16x32_bf16(mf, wf, acc[j], 0, 0, 0);
            acc[j] = __builtin_amdgcn_mfma_f32_16x16x32_bf16(xh, bf, acc[j], 0, 0, 0);
        }
    }

    // C/D layout: col = lane&15, row = quad*4 + reg (verified m89/m91)
    const int rowD0 = b * 64 + rt * 16 + quad * 4;
    #pragma unroll
    for (int j = 0; j < 2; ++j) {
        #pragma unroll
        for (int r = 0; r < 4; ++r) {
            int row = rowD0 + r;
            if (row < NN) out[(size_t)row * DD + (cg * 2 + j) * 16 + m] = acc[j][r];
        }
    }
}

extern "C" void kernel_launch(void* const* d_in, const int* in_sizes, int n_in,
                              void* d_out, int out_size, void* d_ws, size_t ws_size,
                              hipStream_t stream) {
    const float* x  = (const float*)d_in[0];
    const int*   ei = (const int*)d_in[1];   // [2, NE] int32
    const float* W  = (const float*)d_in[2];
    const float* Bm = (const float*)d_in[3];
    float* out = (float*)d_out;

    unsigned int* xb     = (unsigned int*)d_ws;                  // NN*32 uints (6.4 MB)
    int* ebuf            = (int*)(xb + (size_t)NN * 32);         // NBK*MAXB ints (8 MB)
    unsigned short* Wbf  = (unsigned short*)(ebuf + (size_t)NBK * MAXB); // DD*DD bf16
    unsigned short* Bbf  = Wbf + DD * DD;                        // DD*DD bf16
    int* gcursor         = (int*)(Bbf + DD * DD);                // NBK ints

    hipMemsetAsync(gcursor, 0, NBK * sizeof(int), stream);
    convscatter_k<<<NCB, 1024, 0, stream>>>(ei, x, W, Bm, xb, Wbf, Bbf, gcursor, ebuf);
    aggemm_k<<<NBK, 1024, 0, stream>>>(xb, ebuf, gcursor, Wbf, Bbf, x, out);
}

// Round 11
// 141.921 us; speedup vs baseline: 2.7006x; 1.2538x over previous
//
#include <hip/hip_runtime.h>
#include <hip/hip_bf16.h>

#define NN 50000
#define NE 1600000
#define DD 128
#define NPB 64                 // nodes per bucket (dst>>6)
#define NBK 782                // ceil(NN/64)
#define SMAX 3072              // sortagg LDS slab capacity (mean 2048, +20 sigma)
#define CHUNK 3072             // edges per conv chunk
#define NCB 521                // ceil(NE/CHUNK)
#define OTS 784                // offtab row stride (u16): 783 entries padded
#define WS 136                 // gemm LDS row stride (bf16 elems): balanced banks

typedef __attribute__((ext_vector_type(8))) short short8;
typedef __attribute__((ext_vector_type(4))) float f32x4;

__device__ inline unsigned short to_bf16(float v) {
    __hip_bfloat16 h = __float2bfloat16(v);
    return __builtin_bit_cast(unsigned short, h);
}
__device__ inline float bf2f(unsigned short u) {
    return __uint_as_float((unsigned)u << 16);
}

// ---- phase 1: x->fp8 + W/B->bf16 + per-chunk bucket sort, DENSE write -------
// CSR inversion of the old scatter: sorted chunk written contiguously at
// e0 (coalesced dwordx4, no write amplification), per-chunk bucket offsets
// to offtab[c][0..782] (u16). Deletes global atomics, gcursor, memset node.
__global__ __launch_bounds__(1024) void convscatter_k(const int* __restrict__ ei,
                                                      const float* __restrict__ x,
                                                      const float* __restrict__ W,
                                                      const float* __restrict__ Bm,
                                                      unsigned int* __restrict__ xb,
                                                      unsigned short* __restrict__ Wbf,
                                                      unsigned short* __restrict__ Bbf,
                                                      int* __restrict__ ebuf,
                                                      unsigned short* __restrict__ offtab) {
    __shared__ int stg[CHUNK];        // 12 KB
    __shared__ int h[NBK];
    __shared__ int lbase[NBK];
    __shared__ int hcur[NBK];
    __shared__ int wsum[16], wbase[16];
    const int t = threadIdx.x;
    const int lane = t & 63, wv = t >> 6;
    const int e0 = blockIdx.x * CHUNK;
    const int ec = min(CHUNK, NE - e0);

    for (int i = t; i < NBK; i += 1024) h[i] = 0;
    __syncthreads();

    unsigned int w2[3];
    #pragma unroll
    for (int u = 0; u < 3; ++u) {
        int i = u * 1024 + t;
        if (i < ec) {
            int src = ei[e0 + i];
            int dst = ei[NE + e0 + i];
            int b = dst >> 6;
            w2[u] = ((unsigned)b << 22) | ((unsigned)src << 6) | (unsigned)(dst & 63);
            atomicAdd(&h[b], 1);
        } else w2[u] = 0xFFFFFFFFu;
    }

    // independent: convert x (fp32) -> xb (packed 4x fp8-e4m3 per uint)
    {
        int gid = blockIdx.x * 1024 + t;
        const int total4 = NN * DD / 4;
        for (int i = gid; i < total4; i += NCB * 1024) {
            float4 v = ((const float4*)x)[i];
            int p = __builtin_amdgcn_cvt_pk_fp8_f32(v.x, v.y, 0, false);
            p = __builtin_amdgcn_cvt_pk_fp8_f32(v.z, v.w, p, true);
            xb[i] = (unsigned)p;
        }
    }
    // independent: convert W,B (fp32) -> bf16, last block
    if (blockIdx.x == NCB - 1) {
        for (int i = t; i < DD * DD / 4; i += 1024) {
            float4 w4 = ((const float4*)W)[i];
            float4 b4 = ((const float4*)Bm)[i];
            ushort4 wp, bp;
            wp.x = to_bf16(w4.x); wp.y = to_bf16(w4.y); wp.z = to_bf16(w4.z); wp.w = to_bf16(w4.w);
            bp.x = to_bf16(b4.x); bp.y = to_bf16(b4.y); bp.z = to_bf16(b4.z); bp.w = to_bf16(b4.w);
            ((ushort4*)Wbf)[i] = wp;
            ((ushort4*)Bbf)[i] = bp;
        }
    }
    __syncthreads();

    // hierarchical scan over NBK buckets (1 per thread, 2 barriers)
    int v = (t < NBK) ? h[t] : 0;
    int s = v;
    #pragma unroll
    for (int o = 1; o < 64; o <<= 1) {
        int u = __shfl_up(s, o);
        if (lane >= o) s += u;
    }
    if (lane == 63) wsum[wv] = s;
    __syncthreads();
    if (wv == 0 && lane < 16) {
        int bv = wsum[lane];
        int bs = bv;
        #pragma unroll
        for (int o = 1; o < 16; o <<= 1) {
            int u = __shfl_up(bs, o);
            if (lane >= o) bs += u;
        }
        wbase[lane] = bs - bv;
    }
    __syncthreads();
    if (t < NBK) {
        int excl = s - v + wbase[wv];
        lbase[t] = excl;
        hcur[t] = excl;
    }
    __syncthreads();

    // CSR row: offtab[c][b] = in-chunk exclusive offset; [NBK] = ec sentinel
    for (int i = t; i <= NBK; i += 1024)
        offtab[(size_t)blockIdx.x * OTS + i] = (unsigned short)((i < NBK) ? lbase[i] : ec);

    // LDS counting sort (store bucket-stripped payload)
    #pragma unroll
    for (int u = 0; u < 3; ++u) {
        if (w2[u] != 0xFFFFFFFFu) {
            int b = w2[u] >> 22;
            int pos = atomicAdd(&hcur[b], 1);
            stg[pos] = (int)(w2[u] & 0x3FFFFFu);
        }
    }
    __syncthreads();

    // dense coalesced write (all chunk lengths divisible by 4)
    for (int i = t; i < (ec >> 2); i += 1024)
        ((int4*)(ebuf + e0))[i] = ((const int4*)stg)[i];
}

// ---- phase 2: CSR gather-stage + node sort + fp8 aggregation ----------------
// One 1024-thr block per bucket. Stage = edge-parallel binary search over the
// 521 per-chunk segments (scan of offtab column); rest verbatim round-7.
#define ACC2(U)                                                              \
    {                                                                        \
        auto l0 = __builtin_amdgcn_cvt_pk_f32_fp8((int)(U).x, false);        \
        auto h0 = __builtin_amdgcn_cvt_pk_f32_fp8((int)(U).x, true);         \
        auto l1 = __builtin_amdgcn_cvt_pk_f32_fp8((int)(U).y, false);        \
        auto h1 = __builtin_amdgcn_cvt_pk_f32_fp8((int)(U).y, true);         \
        a0 += l0[0]; a1 += l0[1]; a2 += h0[0]; a3 += h0[1];                  \
        a4 += l1[0]; a5 += l1[1]; a6 += h1[0]; a7 += h1[1];                  \
    }

__global__ __launch_bounds__(1024) void sortagg_k(const unsigned int* __restrict__ xb,
                                                  const int* __restrict__ ebuf,
                                                  const unsigned short* __restrict__ offtab,
                                                  unsigned short* __restrict__ psb,
                                                  unsigned short* __restrict__ pcnt) {
    __shared__ int stg[SMAX];                    // 12 KB
    __shared__ unsigned short srt[SMAX];         // 6 KB
    __shared__ int cnt16[16][NPB];               // 4 KB (wave-private)
    __shared__ int cur[NPB], off[NPB + 1];
    __shared__ int segoff[NCB + 1];              // 2.1 KB
    __shared__ int srcb[NCB];                    // 2.1 KB
    __shared__ int ws16[16], wb16[16];
    const int b = blockIdx.x, t = threadIdx.x;
    const int wv = t >> 6, lane = t & 63;

    // 1. offtab column read + 1024-thread scan -> segment offsets
    int v = 0;
    if (t < NCB) {
        int o1 = offtab[(size_t)t * OTS + b];
        int o2 = offtab[(size_t)t * OTS + b + 1];
        v = o2 - o1;
        srcb[t] = t * CHUNK + o1;
    }
    int s = v;
    #pragma unroll
    for (int o = 1; o < 64; o <<= 1) {
        int u = __shfl_up(s, o);
        if (lane >= o) s += u;
    }
    if (lane == 63) ws16[wv] = s;
    cnt16[wv][lane] = 0;
    __syncthreads();
    if (wv == 0 && lane < 16) {
        int bv = ws16[lane], bs = bv;
        #pragma unroll
        for (int o = 1; o < 16; o <<= 1) {
            int u = __shfl_up(bs, o);
            if (lane >= o) bs += u;
        }
        wb16[lane] = bs - bv;
    }
    __syncthreads();
    int excl = s - v + wb16[wv];
    if (t < NCB) segoff[t] = excl;
    if (t == NCB - 1) segoff[NCB] = excl + v;
    __syncthreads();
    const int n = min(segoff[NCB], SMAX);

    // 2. edge-parallel CSR stage (binary search over 522-entry segoff) + hist
    for (int i = t; i < n; i += 1024) {
        int lo = 0, hi = NCB - 1;
        #pragma unroll
        for (int it = 0; it < 10; ++it) {
            int mid = (lo + hi + 1) >> 1;
            if (segoff[mid] <= i) lo = mid; else hi = mid - 1;
        }
        int val = ebuf[srcb[lo] + (i - segoff[lo])];
        stg[i] = val;
        atomicAdd(&cnt16[wv][val & 63], 1);
    }
    __syncthreads();

    // 3. node-level counting sort (verbatim round 7)
    if (t < 64) {
        int vv = 0;
        #pragma unroll
        for (int w = 0; w < 16; ++w) vv += cnt16[w][t];
        int ss = vv;
        #pragma unroll
        for (int o = 1; o < 64; o <<= 1) {
            int u = __shfl_up(ss, o);
            if (t >= o) ss += u;
        }
        cur[t] = ss - vv;
        off[t] = ss - vv;
        if (t == 63) off[64] = ss;
    }
    __syncthreads();
    for (int i = t; i < n; i += 1024) {
        int w = stg[i];
        int pos = atomicAdd(&cur[w & 63], 1);
        srt[pos] = (unsigned short)(w >> 6);
    }
    __syncthreads();

    // 4. gather + sum (verbatim round 7: uint2 per lane, 16 lanes per edge-row)
    const int sub = lane >> 4, il2 = lane & 15;
    #pragma unroll
    for (int q = 0; q < 4; ++q) {
        int ln = wv + q * 16;
        int s0 = off[ln], s1 = off[ln + 1];
        float a0 = 0.f, a1 = 0.f, a2 = 0.f, a3 = 0.f;
        float a4 = 0.f, a5 = 0.f, a6 = 0.f, a7 = 0.f;
        int i = s0;
        for (; i + 16 <= s1; i += 16) {
            uint2 u[4];
            #pragma unroll
            for (int k = 0; k < 4; ++k)
                u[k] = ((const uint2*)xb)[(size_t)srt[i + 4 * k + sub] * 16 + il2];
            #pragma unroll
            for (int k = 0; k < 4; ++k) ACC2(u[k]);
        }
        if (i < s1) {
            uint2 u[4];
            #pragma unroll
            for (int k = 0; k < 4; ++k) {
                int e = i + 4 * k + sub;
                if (e < s1) u[k] = ((const uint2*)xb)[(size_t)srt[e] * 16 + il2];
                else { u[k].x = 0u; u[k].y = 0u; }
            }
            #pragma unroll
            for (int k = 0; k < 4; ++k) ACC2(u[k]);
        }
        a0 += __shfl_xor(a0, 16); a0 += __shfl_xor(a0, 32);
        a1 += __shfl_xor(a1, 16); a1 += __shfl_xor(a1, 32);
        a2 += __shfl_xor(a2, 16); a2 += __shfl_xor(a2, 32);
        a3 += __shfl_xor(a3, 16); a3 += __shfl_xor(a3, 32);
        a4 += __shfl_xor(a4, 16); a4 += __shfl_xor(a4, 32);
        a5 += __shfl_xor(a5, 16); a5 += __shfl_xor(a5, 32);
        a6 += __shfl_xor(a6, 16); a6 += __shfl_xor(a6, 32);
        a7 += __shfl_xor(a7, 16); a7 += __shfl_xor(a7, 32);
        int node = b * NPB + ln;
        if (node < NN) {
            if (lane < 16) {
                short8 sv;
                sv[0] = (short)to_bf16(a0); sv[1] = (short)to_bf16(a1);
                sv[2] = (short)to_bf16(a2); sv[3] = (short)to_bf16(a3);
                sv[4] = (short)to_bf16(a4); sv[5] = (short)to_bf16(a5);
                sv[6] = (short)to_bf16(a6); sv[7] = (short)to_bf16(a7);
                *(short8*)&psb[(size_t)node * DD + il2 * 8] = sv;
            }
            if (lane == 0) pcnt[node] = (unsigned short)(s1 - s0);
        }
    }
}

// ---- phase 3: MFMA epilogue out = (sum/deg) @ W^T + x @ B^T (verbatim R7) ---
__global__ __launch_bounds__(512) void gemm_mfma_k(const unsigned short* __restrict__ psb,
                                                   const unsigned short* __restrict__ pcnt,
                                                   const float* __restrict__ x,
                                                   const unsigned short* __restrict__ Wbf,
                                                   const unsigned short* __restrict__ Bbf,
                                                   float* __restrict__ out) {
    __shared__ unsigned short Wt[DD * WS];   // 34.8 KB
    __shared__ unsigned short Bt[DD * WS];   // 34.8 KB
    const int tid = threadIdx.x;
    #pragma unroll
    for (int it = 0; it < 8; ++it) {
        int idx = it * 512 + tid;
        int n = idx >> 5;
        int k0 = (idx & 31) * 4;
        *(ushort4*)&Wt[n * WS + k0] = ((const ushort4*)Wbf)[idx];
        *(ushort4*)&Bt[n * WS + k0] = ((const ushort4*)Bbf)[idx];
    }
    __syncthreads();

    const int wave = tid >> 6;
    const int lane = tid & 63;
    const int m = lane & 15;
    const int quad = lane >> 4;
    const int rowA = min(blockIdx.x * 128 + wave * 16 + m, NN - 1);

    const float deg = (float)pcnt[rowA];
    const float inv = 1.0f / fmaxf(deg, 1.0f);

    f32x4 acc[8];
    #pragma unroll
    for (int nt = 0; nt < 8; ++nt) acc[nt] = (f32x4){0.f, 0.f, 0.f, 0.f};

    #pragma unroll
    for (int t = 0; t < 4; ++t) {
        const int k8 = t * 32 + quad * 8;
        short8 p0 = *(const short8*)&psb[(size_t)rowA * DD + k8];
        short8 mf;
        #pragma unroll
        for (int j = 0; j < 8; ++j)
            mf[j] = (short)to_bf16(bf2f((unsigned short)p0[j]) * inv);

        float xv[8];
        {
            const float4* xq = (const float4*)&x[(size_t)rowA * DD + k8];
            float4 b0 = xq[0], b1 = xq[1];
            xv[0] = b0.x; xv[1] = b0.y; xv[2] = b0.z; xv[3] = b0.w;
            xv[4] = b1.x; xv[5] = b1.y; xv[6] = b1.z; xv[7] = b1.w;
        }
        short8 xh, xl;
        #pragma unroll
        for (int j = 0; j < 8; ++j) {
            unsigned short g = to_bf16(xv[j]);
            xh[j] = (short)g;
            xl[j] = (short)to_bf16(xv[j] - __uint_as_float((unsigned)g << 16));
        }
        #pragma unroll
        for (int nt = 0; nt < 8; ++nt) {
            int nrow = nt * 16 + m;
            short8 wf = *(const short8*)&Wt[nrow * WS + k8];
            short8 bf = *(const short8*)&Bt[nrow * WS + k8];
            acc[nt] = __builtin_amdgcn_mfma_f32_16x16x32_bf16(xl, bf, acc[nt], 0, 0, 0);
            acc[nt] = __builtin_amdgcn_mfma_f32_16x16x32_bf16(mf, wf, acc[nt], 0, 0, 0);
            acc[nt] = __builtin_amdgcn_mfma_f32_16x16x32_bf16(xh, bf, acc[nt], 0, 0, 0);
        }
    }

    // C/D layout: col = lane&15, row = quad*4 + reg (verified m89/m91)
    const int rowD0 = blockIdx.x * 128 + wave * 16 + quad * 4;
    #pragma unroll
    for (int nt = 0; nt < 8; ++nt) {
        #pragma unroll
        for (int r = 0; r < 4; ++r) {
            int row = rowD0 + r;
            if (row < NN) out[(size_t)row * DD + nt * 16 + m] = acc[nt][r];
        }
    }
}

extern "C" void kernel_launch(void* const* d_in, const int* in_sizes, int n_in,
                              void* d_out, int out_size, void* d_ws, size_t ws_size,
                              hipStream_t stream) {
    const float* x  = (const float*)d_in[0];
    const int*   ei = (const int*)d_in[1];   // [2, NE] int32
    const float* W  = (const float*)d_in[2];
    const float* Bm = (const float*)d_in[3];
    float* out = (float*)d_out;

    unsigned int* xb      = (unsigned int*)d_ws;                 // NN*32 uints (6.4 MB)
    int* ebuf             = (int*)(xb + (size_t)NN * 32);        // NE ints (6.4 MB, dense)
    unsigned short* offtab= (unsigned short*)(ebuf + (size_t)NE);// NCB*OTS u16 (0.82 MB)
    unsigned short* Wbf   = offtab + (size_t)NCB * OTS;          // DD*DD bf16
    unsigned short* Bbf   = Wbf + DD * DD;                       // DD*DD bf16
    unsigned short* psb   = Bbf + DD * DD;                       // NN*DD bf16 (12.8 MB)
    unsigned short* pcnt  = psb + (size_t)NN * DD;               // NN u16

    convscatter_k<<<NCB, 1024, 0, stream>>>(ei, x, W, Bm, xb, Wbf, Bbf, ebuf, offtab);
    sortagg_k<<<NBK, 1024, 0, stream>>>(xb, ebuf, offtab, psb, pcnt);
    gemm_mfma_k<<<(NN + 127) / 128, 512, 0, stream>>>(psb, pcnt, x, Wbf, Bbf, out);
}